// Round 2
// baseline (2090.170 us; speedup 1.0000x reference)
//
#include <hip/hip_runtime.h>

using short8  = __attribute__((ext_vector_type(8))) short;
using floatx4 = __attribute__((ext_vector_type(4))) float;

__device__ __forceinline__ unsigned short f2bf(float x) {
  unsigned int u = __float_as_uint(x);
  return (unsigned short)((u + 0x7FFFu + ((u >> 16) & 1u)) >> 16);
}
__device__ __forceinline__ float bf2f(unsigned short h) {
  return __uint_as_float(((unsigned int)h) << 16);
}

// ---------------- small elementwise / setup kernels ----------------
__global__ void k_fill1(float* __restrict__ p, int n) {
  int i = blockIdx.x * 256 + threadIdx.x;
  if (i < n) p[i] = 1.0f;
}

__global__ void k_edge_deg(const int* __restrict__ ei, float* __restrict__ deg, int E) {
  int e = blockIdx.x * 256 + threadIdx.x;
  if (e < E) atomicAdd(&deg[ei[E + e]], 1.0f);
}

__global__ void k_rsqrt(float* __restrict__ dinv, const float* __restrict__ deg, int n) {
  int i = blockIdx.x * 256 + threadIdx.x;
  if (i < n) dinv[i] = rsqrtf(deg[i]);
}

__global__ void k_f32bf16(const float* __restrict__ src, unsigned short* __restrict__ dst, int n) {
  int i = blockIdx.x * 256 + threadIdx.x;
  if (i < n) dst[i] = f2bf(src[i]);
}

// hi = bf16(x); lo = bf16(x - hi)  -> hi+lo carries ~17 mantissa bits
__global__ void k_f32bf16_split(const float* __restrict__ src, unsigned short* __restrict__ hi,
                                unsigned short* __restrict__ lo, int n) {
  int i = blockIdx.x * 256 + threadIdx.x;
  if (i < n) {
    float x = src[i];
    unsigned short h = f2bf(x);
    hi[i] = h;
    lo[i] = f2bf(x - bf2f(h));
  }
}

// Hb = dinv[n]^2 * h0
__global__ void k_selfinit(float* __restrict__ Hb, const float* __restrict__ h0,
                           const float* __restrict__ dinv, int N) {
  long i = (long)blockIdx.x * 256 + threadIdx.x;
  if (i >= (long)N * 32) return;
  int n = (int)(i >> 5);
  long off = i * 4;
  float s = dinv[n]; s *= s;
  float4 h = *(const float4*)&h0[off];
  float4 o = make_float4(s * h.x, s * h.y, s * h.z, s * h.w);
  *(float4*)&Hb[off] = o;
}

__global__ void k_edge_agg(const int* __restrict__ ei, const float* __restrict__ h0,
                           const float* __restrict__ dinv, float* __restrict__ Hb, int E) {
  long i = (long)blockIdx.x * 256 + threadIdx.x;
  if (i >= (long)E * 32) return;
  int e = (int)(i >> 5), c = (int)(i & 31) * 4;
  int r = ei[e], cl = ei[E + e];
  float nrm = dinv[r] * dinv[cl];
  float4 h = *(const float4*)&h0[(long)r * 128 + c];
  float* dst = &Hb[(long)cl * 128 + c];
  atomicAdd(dst + 0, nrm * h.x);
  atomicAdd(dst + 1, nrm * h.y);
  atomicAdd(dst + 2, nrm * h.z);
  atomicAdd(dst + 3, nrm * h.w);
}

__global__ void k_gcn_final(float* __restrict__ Hb, const float* __restrict__ gcn_b, int N) {
  long i = (long)blockIdx.x * 256 + threadIdx.x;
  if (i >= (long)N * 32) return;
  long off = i * 4;
  int c = (int)(off & 127);
  float4 v = *(float4*)&Hb[off];
  float4 b = *(const float4*)&gcn_b[c];
  v.x = fmaxf(v.x + b.x, 0.f);
  v.y = fmaxf(v.y + b.y, 0.f);
  v.z = fmaxf(v.z + b.z, 0.f);
  v.w = fmaxf(v.w + b.w, 0.f);
  *(float4*)&Hb[off] = v;
}

__global__ void k_final(const float* __restrict__ T, const float* __restrict__ Hb,
                        float* __restrict__ out, int N) {
  long i = (long)blockIdx.x * 256 + threadIdx.x;
  if (i >= (long)N * 32) return;
  long off = i * 4;
  float4 t = *(const float4*)&T[off];
  float4 h = *(const float4*)&Hb[off];
  float4 o;
  o.x = fmaxf(t.x + h.x, 0.f);
  o.y = fmaxf(t.y + h.y, 0.f);
  o.z = fmaxf(t.z + h.z, 0.f);
  o.w = fmaxf(t.w + h.w, 0.f);
  *(float4*)&out[off] = o;
}

// Wc[l] = out_w[l] @ Wv[l]; bc[l] = out_w[l] @ bv[l] + out_b[l]
__global__ void k_combine(const float* __restrict__ in_w, const float* __restrict__ in_b,
                          const float* __restrict__ out_w, const float* __restrict__ out_b,
                          float* __restrict__ Wc, float* __restrict__ bc) {
  __shared__ float Wvs[128][129];
  int l = blockIdx.x;
  const float* Wv = in_w + (long)l * 384 * 128 + 256 * 128;
  const float* bv = in_b + l * 384 + 256;
  const float* Wo = out_w + (long)l * 128 * 128;
  for (int i = threadIdx.x; i < 128 * 128; i += 256)
    Wvs[i >> 7][i & 127] = Wv[i];
  __syncthreads();
  for (int o = threadIdx.x; o < 128 * 128; o += 256) {
    int i = o >> 7, j = o & 127;
    float acc = 0.f;
    for (int k = 0; k < 128; ++k) acc += Wo[i * 128 + k] * Wvs[k][j];
    Wc[(long)l * 16384 + o] = acc;
  }
  if (threadIdx.x < 128) {
    int i = threadIdx.x;
    float acc = out_b[l * 128 + i];
    for (int k = 0; k < 128; ++k) acc += Wo[i * 128 + k] * bv[k];
    bc[l * 128 + i] = acc;
  }
}

// ---------------- MFMA GEMM building blocks ----------------
__device__ __forceinline__ void stage_xf32_split(unsigned short (*dh)[136], unsigned short (*dl)[136],
                                                 const float* __restrict__ src, long row0, int N) {
  #pragma unroll
  for (int it = 0; it < 2; ++it) {
    int i = it * 512 + threadIdx.x;
    int r = i >> 4, c8 = (i & 15) * 8;
    long gr = row0 + r;
    uint4 wh = make_uint4(0u, 0u, 0u, 0u);
    uint4 wl = make_uint4(0u, 0u, 0u, 0u);
    if (gr < N) {
      const float* p = src + gr * 128 + c8;
      float v[8];
      *(float4*)&v[0] = *(const float4*)p;
      *(float4*)&v[4] = *(const float4*)(p + 4);
      unsigned short h[8], l[8];
      #pragma unroll
      for (int j = 0; j < 8; ++j) {
        h[j] = f2bf(v[j]);
        l[j] = f2bf(v[j] - bf2f(h[j]));
      }
      wh.x = (unsigned)h[0] | ((unsigned)h[1] << 16);
      wh.y = (unsigned)h[2] | ((unsigned)h[3] << 16);
      wh.z = (unsigned)h[4] | ((unsigned)h[5] << 16);
      wh.w = (unsigned)h[6] | ((unsigned)h[7] << 16);
      wl.x = (unsigned)l[0] | ((unsigned)l[1] << 16);
      wl.y = (unsigned)l[2] | ((unsigned)l[3] << 16);
      wl.z = (unsigned)l[4] | ((unsigned)l[5] << 16);
      wl.w = (unsigned)l[6] | ((unsigned)l[7] << 16);
    }
    *(uint4*)&dh[r][c8] = wh;
    *(uint4*)&dl[r][c8] = wl;
  }
}

__device__ __forceinline__ void stage_w(unsigned short (*dst)[136], const unsigned short* __restrict__ src,
                                        int ld) {
  #pragma unroll
  for (int it = 0; it < 4; ++it) {
    int i = it * 512 + threadIdx.x;
    int r = i >> 4, c8 = (i & 15) * 8;
    *(uint4*)&dst[r][c8] = *(const uint4*)&src[(long)r * ld + c8];
  }
}

// single-precision-bf16 64x128 GEMM accumulate
__device__ __forceinline__ void mfma_64x128(const unsigned short (*A)[136], const unsigned short (*B)[136],
                                            floatx4 acc[2][2]) {
  int lane = threadIdx.x & 63;
  int wave = threadIdx.x >> 6;
  int wr = (wave >> 2) * 32;
  int wc = (wave & 3) * 32;
  int r16 = lane & 15;
  int k8 = (lane >> 4) * 8;
  #pragma unroll
  for (int ks = 0; ks < 4; ++ks) {
    int k0 = ks * 32 + k8;
    short8 a0 = *(const short8*)&A[wr + r16][k0];
    short8 a1 = *(const short8*)&A[wr + 16 + r16][k0];
    short8 b0 = *(const short8*)&B[wc + r16][k0];
    short8 b1 = *(const short8*)&B[wc + 16 + r16][k0];
    acc[0][0] = __builtin_amdgcn_mfma_f32_16x16x32_bf16(a0, b0, acc[0][0], 0, 0, 0);
    acc[0][1] = __builtin_amdgcn_mfma_f32_16x16x32_bf16(a0, b1, acc[0][1], 0, 0, 0);
    acc[1][0] = __builtin_amdgcn_mfma_f32_16x16x32_bf16(a1, b0, acc[1][0], 0, 0, 0);
    acc[1][1] = __builtin_amdgcn_mfma_f32_16x16x32_bf16(a1, b1, acc[1][1], 0, 0, 0);
  }
}

// split-bf16 (hi/lo) 64x128 GEMM accumulate: AhBh + AhBl + AlBh (~fp32-accurate products)
__device__ __forceinline__ void mfma_64x128_3(const unsigned short (*Ah)[136], const unsigned short (*Al)[136],
                                              const unsigned short (*Bh)[136], const unsigned short (*Bl)[136],
                                              floatx4 acc[2][2]) {
  int lane = threadIdx.x & 63;
  int wave = threadIdx.x >> 6;
  int wr = (wave >> 2) * 32;
  int wc = (wave & 3) * 32;
  int r16 = lane & 15;
  int k8 = (lane >> 4) * 8;
  #pragma unroll
  for (int ks = 0; ks < 4; ++ks) {
    int k0 = ks * 32 + k8;
    short8 a0h = *(const short8*)&Ah[wr + r16][k0];
    short8 a1h = *(const short8*)&Ah[wr + 16 + r16][k0];
    short8 a0l = *(const short8*)&Al[wr + r16][k0];
    short8 a1l = *(const short8*)&Al[wr + 16 + r16][k0];
    short8 b0h = *(const short8*)&Bh[wc + r16][k0];
    short8 b1h = *(const short8*)&Bh[wc + 16 + r16][k0];
    short8 b0l = *(const short8*)&Bl[wc + r16][k0];
    short8 b1l = *(const short8*)&Bl[wc + 16 + r16][k0];
    acc[0][0] = __builtin_amdgcn_mfma_f32_16x16x32_bf16(a0h, b0h, acc[0][0], 0, 0, 0);
    acc[0][0] = __builtin_amdgcn_mfma_f32_16x16x32_bf16(a0h, b0l, acc[0][0], 0, 0, 0);
    acc[0][0] = __builtin_amdgcn_mfma_f32_16x16x32_bf16(a0l, b0h, acc[0][0], 0, 0, 0);
    acc[0][1] = __builtin_amdgcn_mfma_f32_16x16x32_bf16(a0h, b1h, acc[0][1], 0, 0, 0);
    acc[0][1] = __builtin_amdgcn_mfma_f32_16x16x32_bf16(a0h, b1l, acc[0][1], 0, 0, 0);
    acc[0][1] = __builtin_amdgcn_mfma_f32_16x16x32_bf16(a0l, b1h, acc[0][1], 0, 0, 0);
    acc[1][0] = __builtin_amdgcn_mfma_f32_16x16x32_bf16(a1h, b0h, acc[1][0], 0, 0, 0);
    acc[1][0] = __builtin_amdgcn_mfma_f32_16x16x32_bf16(a1h, b0l, acc[1][0], 0, 0, 0);
    acc[1][0] = __builtin_amdgcn_mfma_f32_16x16x32_bf16(a1l, b0h, acc[1][0], 0, 0, 0);
    acc[1][1] = __builtin_amdgcn_mfma_f32_16x16x32_bf16(a1h, b1h, acc[1][1], 0, 0, 0);
    acc[1][1] = __builtin_amdgcn_mfma_f32_16x16x32_bf16(a1h, b1l, acc[1][1], 0, 0, 0);
    acc[1][1] = __builtin_amdgcn_mfma_f32_16x16x32_bf16(a1l, b1h, acc[1][1], 0, 0, 0);
  }
}

__device__ __forceinline__ void frag_to_ys(float (*Ys)[132], const floatx4 acc[2][2]) {
  int lane = threadIdx.x & 63;
  int wave = threadIdx.x >> 6;
  int row0 = (wave >> 2) * 32 + (lane >> 4) * 4;
  int col0 = (wave & 3) * 32 + (lane & 15);
  #pragma unroll
  for (int mi = 0; mi < 2; ++mi)
    #pragma unroll
    for (int ni = 0; ni < 2; ++ni)
      #pragma unroll
      for (int r = 0; r < 4; ++r)
        Ys[row0 + mi * 16 + r][col0 + ni * 16] = acc[mi][ni][r];
}

__device__ __forceinline__ void ln_store(const float (*Ys)[132],
    const float* __restrict__ bias, const float* __restrict__ res,
    const float* __restrict__ g, const float* __restrict__ bl,
    float* __restrict__ Y, long row0, int N) {
  int r = threadIdx.x >> 3;
  int seg = (threadIdx.x & 7) * 16;
  long gr = row0 + r;
  float y[16];
  float s = 0.f, s2 = 0.f;
  if (gr < N) {
    #pragma unroll
    for (int q = 0; q < 4; ++q) {
      float4 v  = *(const float4*)&Ys[r][seg + q * 4];
      float4 b4 = *(const float4*)&bias[seg + q * 4];
      float4 rv = *(const float4*)&res[gr * 128 + seg + q * 4];
      float t0 = v.x + b4.x + rv.x;
      float t1 = v.y + b4.y + rv.y;
      float t2 = v.z + b4.z + rv.z;
      float t3 = v.w + b4.w + rv.w;
      y[q*4+0] = t0; y[q*4+1] = t1; y[q*4+2] = t2; y[q*4+3] = t3;
      s  += t0 + t1 + t2 + t3;
      s2 += t0*t0 + t1*t1 + t2*t2 + t3*t3;
    }
  } else {
    #pragma unroll
    for (int q = 0; q < 16; ++q) y[q] = 0.f;
  }
  #pragma unroll
  for (int off = 1; off < 8; off <<= 1) {
    s  += __shfl_xor(s, off);
    s2 += __shfl_xor(s2, off);
  }
  float m   = s * (1.f / 128.f);
  float var = s2 * (1.f / 128.f) - m * m;
  float inv = rsqrtf(var + 1e-5f);
  if (gr < N) {
    #pragma unroll
    for (int q = 0; q < 4; ++q) {
      float4 g4 = *(const float4*)&g[seg + q * 4];
      float4 b4 = *(const float4*)&bl[seg + q * 4];
      float4 o;
      o.x = (y[q*4+0] - m) * inv * g4.x + b4.x;
      o.y = (y[q*4+1] - m) * inv * g4.y + b4.y;
      o.z = (y[q*4+2] - m) * inv * g4.z + b4.z;
      o.w = (y[q*4+3] - m) * inv * g4.w + b4.w;
      *(float4*)&Y[gr * 128 + seg + q * 4] = o;
    }
  }
}

// ---------------- big kernels ----------------
__global__ __launch_bounds__(512) void k_gemm_plain(const float* __restrict__ X,
    const unsigned short* __restrict__ Wh, const unsigned short* __restrict__ Wl,
    float* __restrict__ Y, int N) {
  __shared__ __align__(16) unsigned short XsH[64][136];
  __shared__ __align__(16) unsigned short XsL[64][136];
  __shared__ __align__(16) unsigned short WsH[128][136];
  __shared__ __align__(16) unsigned short WsL[128][136];
  long row0 = (long)blockIdx.x * 64;
  stage_xf32_split(XsH, XsL, X, row0, N);
  stage_w(WsH, Wh, 128);
  stage_w(WsL, Wl, 128);
  __syncthreads();
  floatx4 zero = {0.f, 0.f, 0.f, 0.f};
  floatx4 acc[2][2] = {{zero, zero}, {zero, zero}};
  mfma_64x128_3(XsH, XsL, WsH, WsL, acc);
  int lane = threadIdx.x & 63;
  int wave = threadIdx.x >> 6;
  int rowb = (wave >> 2) * 32 + (lane >> 4) * 4;
  int colb = (wave & 3) * 32 + (lane & 15);
  #pragma unroll
  for (int mi = 0; mi < 2; ++mi)
    #pragma unroll
    for (int ni = 0; ni < 2; ++ni)
      #pragma unroll
      for (int r = 0; r < 4; ++r) {
        long gr = row0 + rowb + mi * 16 + r;
        if (gr < N) Y[gr * 128 + colb + ni * 16] = acc[mi][ni][r];
      }
}

__global__ __launch_bounds__(512) void k_gemm_ln(const float* __restrict__ X,
    const unsigned short* __restrict__ Wh, const unsigned short* __restrict__ Wl,
    const float* __restrict__ bias,
    const float* __restrict__ g, const float* __restrict__ bl,
    float* __restrict__ Y, int N) {
  __shared__ __align__(16) unsigned short XsH[64][136];
  __shared__ __align__(16) unsigned short XsL[64][136];
  __shared__ union __align__(16) WY {
    struct { unsigned short h[128][136]; unsigned short l[128][136]; } w;
    float ys[64][132];
  } wy;
  long row0 = (long)blockIdx.x * 64;
  stage_xf32_split(XsH, XsL, X, row0, N);
  stage_w(wy.w.h, Wh, 128);
  stage_w(wy.w.l, Wl, 128);
  __syncthreads();
  floatx4 zero = {0.f, 0.f, 0.f, 0.f};
  floatx4 acc[2][2] = {{zero, zero}, {zero, zero}};
  mfma_64x128_3(XsH, XsL, wy.w.h, wy.w.l, acc);
  __syncthreads();
  frag_to_ys(wy.ys, acc);
  __syncthreads();
  ln_store(wy.ys, bias, X, g, bl, Y, row0, N);
}

// t_out = LN2( t1 + relu(t1@W1^T + b1)@W2^T + b2 ); FF chunked by 128.
// W1 split hi/lo; Z and W2 single bf16 (error contribution provably negligible).
// Zs aliases the W1-lo LDS region (extra barrier after phase A).
__global__ __launch_bounds__(512) void k_ffn(const float* __restrict__ T1,
    const unsigned short* __restrict__ W1h, const unsigned short* __restrict__ W1l,
    const float* __restrict__ b1,
    const unsigned short* __restrict__ W2b, const float* __restrict__ b2,
    const float* __restrict__ g, const float* __restrict__ bl,
    float* __restrict__ Y, int N) {
  __shared__ __align__(16) unsigned short XsH[64][136];
  __shared__ __align__(16) unsigned short XsL[64][136];
  __shared__ __align__(16) unsigned short W2s[128][136];
  __shared__ union __align__(16) WY {
    struct { unsigned short h[128][136]; unsigned short l[128][136]; } w1;
    float ys[64][132];
  } wy;
  long row0 = (long)blockIdx.x * 64;
  stage_xf32_split(XsH, XsL, T1, row0, N);
  floatx4 zero = {0.f, 0.f, 0.f, 0.f};
  floatx4 acc2[2][2] = {{zero, zero}, {zero, zero}};
  int lane = threadIdx.x & 63;
  int wave = threadIdx.x >> 6;
  int wr = (wave >> 2) * 32;
  int wc = (wave & 3) * 32;
  int zr0 = wr + (lane >> 4) * 4;
  int zc0 = wc + (lane & 15);
  unsigned short (*Zs)[136] = wy.w1.l;   // aliased: w1.l dead after phase A
  for (int fc = 0; fc < 2048; fc += 128) {
    __syncthreads();                     // prev chunk's phase-B readers done
    stage_w(wy.w1.h, W1h + (long)fc * 128, 128);
    stage_w(wy.w1.l, W1l + (long)fc * 128, 128);
    stage_w(W2s, W2b + fc, 2048);
    __syncthreads();                     // staging visible (covers Xs on iter 0)
    floatx4 acc1[2][2] = {{zero, zero}, {zero, zero}};
    mfma_64x128_3(XsH, XsL, wy.w1.h, wy.w1.l, acc1);
    float bv0 = b1[fc + wc + (lane & 15)];
    float bv1 = b1[fc + wc + 16 + (lane & 15)];
    __syncthreads();                     // all phase-A reads of w1.l done before Zs overlay
    #pragma unroll
    for (int mi = 0; mi < 2; ++mi)
      #pragma unroll
      for (int ni = 0; ni < 2; ++ni) {
        float bv = ni ? bv1 : bv0;
        #pragma unroll
        for (int r = 0; r < 4; ++r) {
          float z = fmaxf(acc1[mi][ni][r] + bv, 0.f);
          Zs[zr0 + mi * 16 + r][zc0 + ni * 16] = f2bf(z);
        }
      }
    __syncthreads();                     // Zs visible
    mfma_64x128(Zs, W2s, acc2);
  }
  __syncthreads();                       // last phase-B done before ys overlays w1
  frag_to_ys(wy.ys, acc2);
  __syncthreads();
  ln_store(wy.ys, b2, T1, g, bl, Y, row0, N);
}

// ---------------- launcher ----------------
extern "C" void kernel_launch(void* const* d_in, const int* in_sizes, int n_in,
                              void* d_out, int out_size, void* d_ws, size_t ws_size,
                              hipStream_t stream) {
  const int N = in_sizes[0] / 128;
  const int E = in_sizes[1] / 2;
  const float* x     = (const float*)d_in[0];
  const int*   ei    = (const int*)d_in[1];
  const float* gcn_w = (const float*)d_in[2];
  const float* gcn_b = (const float*)d_in[3];
  const float* in_w  = (const float*)d_in[4];
  const float* in_b  = (const float*)d_in[5];
  const float* out_w = (const float*)d_in[6];
  const float* out_b = (const float*)d_in[7];
  const float* ln1_g = (const float*)d_in[8];
  const float* ln1_b = (const float*)d_in[9];
  const float* ff1_w = (const float*)d_in[10];
  const float* ff1_b = (const float*)d_in[11];
  const float* ff2_w = (const float*)d_in[12];
  const float* ff2_b = (const float*)d_in[13];
  const float* ln2_g = (const float*)d_in[14];
  const float* ln2_b = (const float*)d_in[15];
  float* out = (float*)d_out;

  char* w = (char*)d_ws;
  auto alloc = [&](size_t bytes) { char* p = w; w += (bytes + 255) & ~(size_t)255; return p; };
  float* deg  = (float*)alloc((size_t)N * 4);
  float* dinv = (float*)alloc((size_t)N * 4);
  float* h0   = (float*)alloc((size_t)N * 128 * 4);   // reused as B2
  float* Hb   = (float*)alloc((size_t)N * 128 * 4);
  float* B1   = (float*)alloc((size_t)N * 128 * 4);
  float* Wc   = (float*)alloc(2 * 16384 * 4);
  float* bc   = (float*)alloc(2 * 128 * 4);
  unsigned short* gcnh = (unsigned short*)alloc(16384 * 2);
  unsigned short* gcnl = (unsigned short*)alloc(16384 * 2);
  unsigned short* Wch  = (unsigned short*)alloc(2 * 16384 * 2);
  unsigned short* Wcl  = (unsigned short*)alloc(2 * 16384 * 2);
  unsigned short* ff1h = (unsigned short*)alloc(2 * 262144 * 2);
  unsigned short* ff1l = (unsigned short*)alloc(2 * 262144 * 2);
  unsigned short* ff2h = (unsigned short*)alloc(2 * 262144 * 2);
  float* B2 = h0;

  const int gN = (N + 255) / 256;
  const int gT = (N + 63) / 64;
  const int gV = (int)(((long)N * 32 + 255) / 256);
  const int gE = (int)(((long)E * 32 + 255) / 256);

  k_fill1<<<gN, 256, 0, stream>>>(deg, N);
  k_edge_deg<<<(E + 255) / 256, 256, 0, stream>>>(ei, deg, E);
  k_rsqrt<<<gN, 256, 0, stream>>>(dinv, deg, N);
  k_combine<<<2, 256, 0, stream>>>(in_w, in_b, out_w, out_b, Wc, bc);
  k_f32bf16_split<<<(16384 + 255) / 256, 256, 0, stream>>>(gcn_w, gcnh, gcnl, 16384);
  k_f32bf16_split<<<(32768 + 255) / 256, 256, 0, stream>>>(Wc, Wch, Wcl, 32768);
  k_f32bf16_split<<<(524288 + 255) / 256, 256, 0, stream>>>(ff1_w, ff1h, ff1l, 524288);
  k_f32bf16<<<(524288 + 255) / 256, 256, 0, stream>>>(ff2_w, ff2h, 524288);

  k_gemm_plain<<<gT, 512, 0, stream>>>(x, gcnh, gcnl, h0, N);
  k_selfinit<<<gV, 256, 0, stream>>>(Hb, h0, dinv, N);
  k_edge_agg<<<gE, 256, 0, stream>>>(ei, h0, dinv, Hb, E);
  k_gcn_final<<<gV, 256, 0, stream>>>(Hb, gcn_b, N);

  // layer 0
  k_gemm_ln<<<gT, 512, 0, stream>>>(Hb, Wch, Wcl, bc, ln1_g, ln1_b, B1, N);
  k_ffn<<<gT, 512, 0, stream>>>(B1, ff1h, ff1l, ff1_b, ff2h, ff2_b, ln2_g, ln2_b, B2, N);
  // layer 1
  k_gemm_ln<<<gT, 512, 0, stream>>>(B2, Wch + 16384, Wcl + 16384, bc + 128,
                                    ln1_g + 128, ln1_b + 128, B1, N);
  k_ffn<<<gT, 512, 0, stream>>>(B1, ff1h + 262144, ff1l + 262144, ff1_b + 2048,
                                ff2h + 262144, ff2_b + 128, ln2_g + 128, ln2_b + 128, B2, N);

  k_final<<<gV, 256, 0, stream>>>(B2, Hb, out, N);
}

// Round 3
// 882.397 us; speedup vs baseline: 2.3687x; 2.3687x over previous
//
#include <hip/hip_runtime.h>

using short8  = __attribute__((ext_vector_type(8))) short;
using floatx4 = __attribute__((ext_vector_type(4))) float;

__device__ __forceinline__ unsigned short f2bf(float x) {
  unsigned int u = __float_as_uint(x);
  return (unsigned short)((u + 0x7FFFu + ((u >> 16) & 1u)) >> 16);
}
__device__ __forceinline__ float bf2f(unsigned short h) {
  return __uint_as_float(((unsigned int)h) << 16);
}

// ---------------- small elementwise / setup kernels ----------------
__global__ void k_fill1(float* __restrict__ p, int n) {
  int i = blockIdx.x * 256 + threadIdx.x;
  if (i < n) p[i] = 1.0f;
}

__global__ void k_edge_deg(const int* __restrict__ ei, float* __restrict__ deg, int E) {
  int e = blockIdx.x * 256 + threadIdx.x;
  if (e < E) atomicAdd(&deg[ei[E + e]], 1.0f);
}

__global__ void k_rsqrt(float* __restrict__ dinv, const float* __restrict__ deg, int n) {
  int i = blockIdx.x * 256 + threadIdx.x;
  if (i < n) dinv[i] = rsqrtf(deg[i]);
}

__global__ void k_f32bf16(const float* __restrict__ src, unsigned short* __restrict__ dst, int n) {
  int i = blockIdx.x * 256 + threadIdx.x;
  if (i < n) dst[i] = f2bf(src[i]);
}

// hi = bf16(x); lo = bf16(x - hi)
__global__ void k_f32bf16_split(const float* __restrict__ src, unsigned short* __restrict__ hi,
                                unsigned short* __restrict__ lo, int n) {
  int i = blockIdx.x * 256 + threadIdx.x;
  if (i < n) {
    float x = src[i];
    unsigned short h = f2bf(x);
    hi[i] = h;
    lo[i] = f2bf(x - bf2f(h));
  }
}

// ---------------- CSR build: scan + scatter ----------------
// off[i] = sum_{j<i} ((int)deg[j]-1); off[N] = E. Single block, 1024 threads.
__global__ __launch_bounds__(1024) void k_scan(const float* __restrict__ deg,
                                               int* __restrict__ off, int N) {
  __shared__ int wsum[16];
  __shared__ int carry;
  if (threadIdx.x == 0) carry = 0;
  int lane = threadIdx.x & 63, wv = threadIdx.x >> 6;
  for (int base = 0; base < N; base += 1024) {
    int i = base + threadIdx.x;
    int c = (i < N) ? ((int)deg[i] - 1) : 0;
    int s = c;
    #pragma unroll
    for (int o = 1; o < 64; o <<= 1) {
      int t = __shfl_up(s, o);
      if (lane >= o) s += t;
    }
    __syncthreads();                 // prior iteration's wsum reads done
    if (lane == 63) wsum[wv] = s;
    __syncthreads();
    int wpre = 0, total = 0;
    #pragma unroll
    for (int w = 0; w < 16; ++w) {
      int v = wsum[w];
      if (w < wv) wpre += v;
      total += v;
    }
    if (i < N) off[i] = carry + wpre + s - c;   // exclusive
    __syncthreads();                 // everyone read carry before update
    if (threadIdx.x == 0) carry += total;
  }
  __syncthreads();
  if (threadIdx.x == 0) off[N] = carry;
}

__global__ void k_scatter(const int* __restrict__ ei, int* __restrict__ cur,
                          int* __restrict__ srcs, int E) {
  int e = blockIdx.x * 256 + threadIdx.x;
  if (e < E) {
    int r = ei[e], c = ei[E + e];
    int p = atomicAdd(&cur[c], 1);
    srcs[p] = r;
  }
}

// one wave per node: Hb[n] = relu( sum_nbr dinv[n]dinv[s] h0[s] + dinv[n]^2 h0[n] + b )
__global__ __launch_bounds__(256) void k_gcn_agg(const int* __restrict__ off,
    const int* __restrict__ srcs, const float* __restrict__ dinv,
    const float* __restrict__ h0, const float* __restrict__ gcn_b,
    float* __restrict__ Hb, int N) {
  int node = blockIdx.x * 4 + (threadIdx.x >> 6);
  if (node >= N) return;
  int c2 = (threadIdx.x & 63) * 2;
  float dc = dinv[node];
  float a0 = 0.f, a1 = 0.f;
  int j = off[node], end = off[node + 1];
  for (; j + 1 < end; j += 2) {
    int s0 = srcs[j], s1 = srcs[j + 1];
    float w0 = dinv[s0] * dc, w1 = dinv[s1] * dc;
    float2 h0v = *(const float2*)&h0[(long)s0 * 128 + c2];
    float2 h1v = *(const float2*)&h0[(long)s1 * 128 + c2];
    a0 += w0 * h0v.x + w1 * h1v.x;
    a1 += w0 * h0v.y + w1 * h1v.y;
  }
  if (j < end) {
    int s0 = srcs[j];
    float w0 = dinv[s0] * dc;
    float2 hv = *(const float2*)&h0[(long)s0 * 128 + c2];
    a0 += w0 * hv.x;
    a1 += w0 * hv.y;
  }
  float2 hv = *(const float2*)&h0[(long)node * 128 + c2];
  float2 b  = *(const float2*)&gcn_b[c2];
  float v0 = a0 + dc * dc * hv.x + b.x;
  float v1 = a1 + dc * dc * hv.y + b.y;
  *(float2*)&Hb[(long)node * 128 + c2] = make_float2(fmaxf(v0, 0.f), fmaxf(v1, 0.f));
}

__global__ void k_final(const float* __restrict__ T, const float* __restrict__ Hb,
                        float* __restrict__ out, int N) {
  long i = (long)blockIdx.x * 256 + threadIdx.x;
  if (i >= (long)N * 32) return;
  long off = i * 4;
  float4 t = *(const float4*)&T[off];
  float4 h = *(const float4*)&Hb[off];
  float4 o;
  o.x = fmaxf(t.x + h.x, 0.f);
  o.y = fmaxf(t.y + h.y, 0.f);
  o.z = fmaxf(t.z + h.z, 0.f);
  o.w = fmaxf(t.w + h.w, 0.f);
  *(float4*)&out[off] = o;
}

// Wc[l] = out_w[l] @ Wv[l]; bc[l] = out_w[l] @ bv[l] + out_b[l]
__global__ void k_combine(const float* __restrict__ in_w, const float* __restrict__ in_b,
                          const float* __restrict__ out_w, const float* __restrict__ out_b,
                          float* __restrict__ Wc, float* __restrict__ bc) {
  __shared__ float Wvs[128][129];
  int l = blockIdx.x;
  const float* Wv = in_w + (long)l * 384 * 128 + 256 * 128;
  const float* bv = in_b + l * 384 + 256;
  const float* Wo = out_w + (long)l * 128 * 128;
  for (int i = threadIdx.x; i < 128 * 128; i += 256)
    Wvs[i >> 7][i & 127] = Wv[i];
  __syncthreads();
  for (int o = threadIdx.x; o < 128 * 128; o += 256) {
    int i = o >> 7, j = o & 127;
    float acc = 0.f;
    for (int k = 0; k < 128; ++k) acc += Wo[i * 128 + k] * Wvs[k][j];
    Wc[(long)l * 16384 + o] = acc;
  }
  if (threadIdx.x < 128) {
    int i = threadIdx.x;
    float acc = out_b[l * 128 + i];
    for (int k = 0; k < 128; ++k) acc += Wo[i * 128 + k] * bv[k];
    bc[l * 128 + i] = acc;
  }
}

// ---------------- MFMA GEMM building blocks ----------------
__device__ __forceinline__ void stage_xf32_split(unsigned short (*dh)[136], unsigned short (*dl)[136],
                                                 const float* __restrict__ src, long row0, int N) {
  #pragma unroll
  for (int it = 0; it < 2; ++it) {
    int i = it * 512 + threadIdx.x;
    int r = i >> 4, c8 = (i & 15) * 8;
    long gr = row0 + r;
    uint4 wh = make_uint4(0u, 0u, 0u, 0u);
    uint4 wl = make_uint4(0u, 0u, 0u, 0u);
    if (gr < N) {
      const float* p = src + gr * 128 + c8;
      float v[8];
      *(float4*)&v[0] = *(const float4*)p;
      *(float4*)&v[4] = *(const float4*)(p + 4);
      unsigned short h[8], l[8];
      #pragma unroll
      for (int j = 0; j < 8; ++j) {
        h[j] = f2bf(v[j]);
        l[j] = f2bf(v[j] - bf2f(h[j]));
      }
      wh.x = (unsigned)h[0] | ((unsigned)h[1] << 16);
      wh.y = (unsigned)h[2] | ((unsigned)h[3] << 16);
      wh.z = (unsigned)h[4] | ((unsigned)h[5] << 16);
      wh.w = (unsigned)h[6] | ((unsigned)h[7] << 16);
      wl.x = (unsigned)l[0] | ((unsigned)l[1] << 16);
      wl.y = (unsigned)l[2] | ((unsigned)l[3] << 16);
      wl.z = (unsigned)l[4] | ((unsigned)l[5] << 16);
      wl.w = (unsigned)l[6] | ((unsigned)l[7] << 16);
    }
    *(uint4*)&dh[r][c8] = wh;
    *(uint4*)&dl[r][c8] = wl;
  }
}

__device__ __forceinline__ void stage_w(unsigned short (*dst)[136], const unsigned short* __restrict__ src,
                                        int ld) {
  #pragma unroll
  for (int it = 0; it < 4; ++it) {
    int i = it * 512 + threadIdx.x;
    int r = i >> 4, c8 = (i & 15) * 8;
    *(uint4*)&dst[r][c8] = *(const uint4*)&src[(long)r * ld + c8];
  }
}

__device__ __forceinline__ void mfma_64x128(const unsigned short (*A)[136], const unsigned short (*B)[136],
                                            floatx4 acc[2][2]) {
  int lane = threadIdx.x & 63;
  int wave = threadIdx.x >> 6;
  int wr = (wave >> 2) * 32;
  int wc = (wave & 3) * 32;
  int r16 = lane & 15;
  int k8 = (lane >> 4) * 8;
  #pragma unroll
  for (int ks = 0; ks < 4; ++ks) {
    int k0 = ks * 32 + k8;
    short8 a0 = *(const short8*)&A[wr + r16][k0];
    short8 a1 = *(const short8*)&A[wr + 16 + r16][k0];
    short8 b0 = *(const short8*)&B[wc + r16][k0];
    short8 b1 = *(const short8*)&B[wc + 16 + r16][k0];
    acc[0][0] = __builtin_amdgcn_mfma_f32_16x16x32_bf16(a0, b0, acc[0][0], 0, 0, 0);
    acc[0][1] = __builtin_amdgcn_mfma_f32_16x16x32_bf16(a0, b1, acc[0][1], 0, 0, 0);
    acc[1][0] = __builtin_amdgcn_mfma_f32_16x16x32_bf16(a1, b0, acc[1][0], 0, 0, 0);
    acc[1][1] = __builtin_amdgcn_mfma_f32_16x16x32_bf16(a1, b1, acc[1][1], 0, 0, 0);
  }
}

__device__ __forceinline__ void mfma_64x128_3(const unsigned short (*Ah)[136], const unsigned short (*Al)[136],
                                              const unsigned short (*Bh)[136], const unsigned short (*Bl)[136],
                                              floatx4 acc[2][2]) {
  int lane = threadIdx.x & 63;
  int wave = threadIdx.x >> 6;
  int wr = (wave >> 2) * 32;
  int wc = (wave & 3) * 32;
  int r16 = lane & 15;
  int k8 = (lane >> 4) * 8;
  #pragma unroll
  for (int ks = 0; ks < 4; ++ks) {
    int k0 = ks * 32 + k8;
    short8 a0h = *(const short8*)&Ah[wr + r16][k0];
    short8 a1h = *(const short8*)&Ah[wr + 16 + r16][k0];
    short8 a0l = *(const short8*)&Al[wr + r16][k0];
    short8 a1l = *(const short8*)&Al[wr + 16 + r16][k0];
    short8 b0h = *(const short8*)&Bh[wc + r16][k0];
    short8 b1h = *(const short8*)&Bh[wc + 16 + r16][k0];
    short8 b0l = *(const short8*)&Bl[wc + r16][k0];
    short8 b1l = *(const short8*)&Bl[wc + 16 + r16][k0];
    acc[0][0] = __builtin_amdgcn_mfma_f32_16x16x32_bf16(a0h, b0h, acc[0][0], 0, 0, 0);
    acc[0][0] = __builtin_amdgcn_mfma_f32_16x16x32_bf16(a0h, b0l, acc[0][0], 0, 0, 0);
    acc[0][0] = __builtin_amdgcn_mfma_f32_16x16x32_bf16(a0l, b0h, acc[0][0], 0, 0, 0);
    acc[0][1] = __builtin_amdgcn_mfma_f32_16x16x32_bf16(a0h, b1h, acc[0][1], 0, 0, 0);
    acc[0][1] = __builtin_amdgcn_mfma_f32_16x16x32_bf16(a0h, b1l, acc[0][1], 0, 0, 0);
    acc[0][1] = __builtin_amdgcn_mfma_f32_16x16x32_bf16(a0l, b1h, acc[0][1], 0, 0, 0);
    acc[1][0] = __builtin_amdgcn_mfma_f32_16x16x32_bf16(a1h, b0h, acc[1][0], 0, 0, 0);
    acc[1][0] = __builtin_amdgcn_mfma_f32_16x16x32_bf16(a1h, b0l, acc[1][0], 0, 0, 0);
    acc[1][0] = __builtin_amdgcn_mfma_f32_16x16x32_bf16(a1l, b0h, acc[1][0], 0, 0, 0);
    acc[1][1] = __builtin_amdgcn_mfma_f32_16x16x32_bf16(a1h, b1h, acc[1][1], 0, 0, 0);
    acc[1][1] = __builtin_amdgcn_mfma_f32_16x16x32_bf16(a1h, b1l, acc[1][1], 0, 0, 0);
    acc[1][1] = __builtin_amdgcn_mfma_f32_16x16x32_bf16(a1l, b1h, acc[1][1], 0, 0, 0);
  }
}

__device__ __forceinline__ void frag_to_ys(float (*Ys)[132], const floatx4 acc[2][2]) {
  int lane = threadIdx.x & 63;
  int wave = threadIdx.x >> 6;
  int row0 = (wave >> 2) * 32 + (lane >> 4) * 4;
  int col0 = (wave & 3) * 32 + (lane & 15);
  #pragma unroll
  for (int mi = 0; mi < 2; ++mi)
    #pragma unroll
    for (int ni = 0; ni < 2; ++ni)
      #pragma unroll
      for (int r = 0; r < 4; ++r)
        Ys[row0 + mi * 16 + r][col0 + ni * 16] = acc[mi][ni][r];
}

__device__ __forceinline__ void ln_store(const float (*Ys)[132],
    const float* __restrict__ bias, const float* __restrict__ res,
    const float* __restrict__ g, const float* __restrict__ bl,
    float* __restrict__ Y, long row0, int N) {
  int r = threadIdx.x >> 3;
  int seg = (threadIdx.x & 7) * 16;
  long gr = row0 + r;
  float y[16];
  float s = 0.f, s2 = 0.f;
  if (gr < N) {
    #pragma unroll
    for (int q = 0; q < 4; ++q) {
      float4 v  = *(const float4*)&Ys[r][seg + q * 4];
      float4 b4 = *(const float4*)&bias[seg + q * 4];
      float4 rv = *(const float4*)&res[gr * 128 + seg + q * 4];
      float t0 = v.x + b4.x + rv.x;
      float t1 = v.y + b4.y + rv.y;
      float t2 = v.z + b4.z + rv.z;
      float t3 = v.w + b4.w + rv.w;
      y[q*4+0] = t0; y[q*4+1] = t1; y[q*4+2] = t2; y[q*4+3] = t3;
      s  += t0 + t1 + t2 + t3;
      s2 += t0*t0 + t1*t1 + t2*t2 + t3*t3;
    }
  } else {
    #pragma unroll
    for (int q = 0; q < 16; ++q) y[q] = 0.f;
  }
  #pragma unroll
  for (int off = 1; off < 8; off <<= 1) {
    s  += __shfl_xor(s, off);
    s2 += __shfl_xor(s2, off);
  }
  float m   = s * (1.f / 128.f);
  float var = s2 * (1.f / 128.f) - m * m;
  float inv = rsqrtf(var + 1e-5f);
  if (gr < N) {
    #pragma unroll
    for (int q = 0; q < 4; ++q) {
      float4 g4 = *(const float4*)&g[seg + q * 4];
      float4 b4 = *(const float4*)&bl[seg + q * 4];
      float4 o;
      o.x = (y[q*4+0] - m) * inv * g4.x + b4.x;
      o.y = (y[q*4+1] - m) * inv * g4.y + b4.y;
      o.z = (y[q*4+2] - m) * inv * g4.z + b4.z;
      o.w = (y[q*4+3] - m) * inv * g4.w + b4.w;
      *(float4*)&Y[gr * 128 + seg + q * 4] = o;
    }
  }
}

// ---------------- big kernels ----------------
__global__ __launch_bounds__(512) void k_gemm_plain(const float* __restrict__ X,
    const unsigned short* __restrict__ Wh, const unsigned short* __restrict__ Wl,
    float* __restrict__ Y, int N) {
  __shared__ __align__(16) unsigned short XsH[64][136];
  __shared__ __align__(16) unsigned short XsL[64][136];
  __shared__ __align__(16) unsigned short WsH[128][136];
  __shared__ __align__(16) unsigned short WsL[128][136];
  long row0 = (long)blockIdx.x * 64;
  stage_xf32_split(XsH, XsL, X, row0, N);
  stage_w(WsH, Wh, 128);
  stage_w(WsL, Wl, 128);
  __syncthreads();
  floatx4 zero = {0.f, 0.f, 0.f, 0.f};
  floatx4 acc[2][2] = {{zero, zero}, {zero, zero}};
  mfma_64x128_3(XsH, XsL, WsH, WsL, acc);
  int lane = threadIdx.x & 63;
  int wave = threadIdx.x >> 6;
  int rowb = (wave >> 2) * 32 + (lane >> 4) * 4;
  int colb = (wave & 3) * 32 + (lane & 15);
  #pragma unroll
  for (int mi = 0; mi < 2; ++mi)
    #pragma unroll
    for (int ni = 0; ni < 2; ++ni)
      #pragma unroll
      for (int r = 0; r < 4; ++r) {
        long gr = row0 + rowb + mi * 16 + r;
        if (gr < N) Y[gr * 128 + colb + ni * 16] = acc[mi][ni][r];
      }
}

__global__ __launch_bounds__(512) void k_gemm_ln(const float* __restrict__ X,
    const unsigned short* __restrict__ Wh, const unsigned short* __restrict__ Wl,
    const float* __restrict__ bias,
    const float* __restrict__ g, const float* __restrict__ bl,
    float* __restrict__ Y, int N) {
  __shared__ __align__(16) unsigned short XsH[64][136];
  __shared__ __align__(16) unsigned short XsL[64][136];
  __shared__ union __align__(16) WY {
    struct { unsigned short h[128][136]; unsigned short l[128][136]; } w;
    float ys[64][132];
  } wy;
  long row0 = (long)blockIdx.x * 64;
  stage_xf32_split(XsH, XsL, X, row0, N);
  stage_w(wy.w.h, Wh, 128);
  stage_w(wy.w.l, Wl, 128);
  __syncthreads();
  floatx4 zero = {0.f, 0.f, 0.f, 0.f};
  floatx4 acc[2][2] = {{zero, zero}, {zero, zero}};
  mfma_64x128_3(XsH, XsL, wy.w.h, wy.w.l, acc);
  __syncthreads();
  frag_to_ys(wy.ys, acc);
  __syncthreads();
  ln_store(wy.ys, bias, X, g, bl, Y, row0, N);
}

__global__ __launch_bounds__(512) void k_ffn(const float* __restrict__ T1,
    const unsigned short* __restrict__ W1h, const unsigned short* __restrict__ W1l,
    const float* __restrict__ b1,
    const unsigned short* __restrict__ W2b, const float* __restrict__ b2,
    const float* __restrict__ g, const float* __restrict__ bl,
    float* __restrict__ Y, int N) {
  __shared__ __align__(16) unsigned short XsH[64][136];
  __shared__ __align__(16) unsigned short XsL[64][136];
  __shared__ __align__(16) unsigned short W2s[128][136];
  __shared__ union __align__(16) WY {
    struct { unsigned short h[128][136]; unsigned short l[128][136]; } w1;
    float ys[64][132];
  } wy;
  long row0 = (long)blockIdx.x * 64;
  stage_xf32_split(XsH, XsL, T1, row0, N);
  floatx4 zero = {0.f, 0.f, 0.f, 0.f};
  floatx4 acc2[2][2] = {{zero, zero}, {zero, zero}};
  int lane = threadIdx.x & 63;
  int wave = threadIdx.x >> 6;
  int wr = (wave >> 2) * 32;
  int wc = (wave & 3) * 32;
  int zr0 = wr + (lane >> 4) * 4;
  int zc0 = wc + (lane & 15);
  unsigned short (*Zs)[136] = wy.w1.l;   // aliased: w1.l dead after phase A
  for (int fc = 0; fc < 2048; fc += 128) {
    __syncthreads();
    stage_w(wy.w1.h, W1h + (long)fc * 128, 128);
    stage_w(wy.w1.l, W1l + (long)fc * 128, 128);
    stage_w(W2s, W2b + fc, 2048);
    __syncthreads();
    floatx4 acc1[2][2] = {{zero, zero}, {zero, zero}};
    mfma_64x128_3(XsH, XsL, wy.w1.h, wy.w1.l, acc1);
    float bv0 = b1[fc + wc + (lane & 15)];
    float bv1 = b1[fc + wc + 16 + (lane & 15)];
    __syncthreads();                     // phase-A reads of w1.l done before Zs overlay
    #pragma unroll
    for (int mi = 0; mi < 2; ++mi)
      #pragma unroll
      for (int ni = 0; ni < 2; ++ni) {
        float bv = ni ? bv1 : bv0;
        #pragma unroll
        for (int r = 0; r < 4; ++r) {
          float z = fmaxf(acc1[mi][ni][r] + bv, 0.f);
          Zs[zr0 + mi * 16 + r][zc0 + ni * 16] = f2bf(z);
        }
      }
    __syncthreads();
    mfma_64x128(Zs, W2s, acc2);
  }
  __syncthreads();
  frag_to_ys(wy.ys, acc2);
  __syncthreads();
  ln_store(wy.ys, b2, T1, g, bl, Y, row0, N);
}

// ---------------- launcher ----------------
extern "C" void kernel_launch(void* const* d_in, const int* in_sizes, int n_in,
                              void* d_out, int out_size, void* d_ws, size_t ws_size,
                              hipStream_t stream) {
  const int N = in_sizes[0] / 128;
  const int E = in_sizes[1] / 2;
  const float* x     = (const float*)d_in[0];
  const int*   ei    = (const int*)d_in[1];
  const float* gcn_w = (const float*)d_in[2];
  const float* gcn_b = (const float*)d_in[3];
  const float* in_w  = (const float*)d_in[4];
  const float* in_b  = (const float*)d_in[5];
  const float* out_w = (const float*)d_in[6];
  const float* out_b = (const float*)d_in[7];
  const float* ln1_g = (const float*)d_in[8];
  const float* ln1_b = (const float*)d_in[9];
  const float* ff1_w = (const float*)d_in[10];
  const float* ff1_b = (const float*)d_in[11];
  const float* ff2_w = (const float*)d_in[12];
  const float* ff2_b = (const float*)d_in[13];
  const float* ln2_g = (const float*)d_in[14];
  const float* ln2_b = (const float*)d_in[15];
  float* out = (float*)d_out;

  char* w = (char*)d_ws;
  auto alloc = [&](size_t bytes) { char* p = w; w += (bytes + 255) & ~(size_t)255; return p; };
  float* deg  = (float*)alloc((size_t)N * 4);
  float* dinv = (float*)alloc((size_t)N * 4);
  int*   off  = (int*)alloc((size_t)(N + 1) * 4);
  int*   cur  = (int*)alloc((size_t)N * 4);
  int*   srcs = (int*)alloc((size_t)E * 4);
  float* h0   = (float*)alloc((size_t)N * 128 * 4);   // reused as B2
  float* Hb   = (float*)alloc((size_t)N * 128 * 4);
  float* B1   = (float*)alloc((size_t)N * 128 * 4);
  float* Wc   = (float*)alloc(2 * 16384 * 4);
  float* bc   = (float*)alloc(2 * 128 * 4);
  unsigned short* gcnh = (unsigned short*)alloc(16384 * 2);
  unsigned short* gcnl = (unsigned short*)alloc(16384 * 2);
  unsigned short* Wch  = (unsigned short*)alloc(2 * 16384 * 2);
  unsigned short* Wcl  = (unsigned short*)alloc(2 * 16384 * 2);
  unsigned short* ff1h = (unsigned short*)alloc(2 * 262144 * 2);
  unsigned short* ff1l = (unsigned short*)alloc(2 * 262144 * 2);
  unsigned short* ff2h = (unsigned short*)alloc(2 * 262144 * 2);
  float* B2 = h0;

  const int gN = (N + 255) / 256;
  const int gT = (N + 63) / 64;
  const int gV = (int)(((long)N * 32 + 255) / 256);

  // CSR build
  k_fill1<<<gN, 256, 0, stream>>>(deg, N);
  k_edge_deg<<<(E + 255) / 256, 256, 0, stream>>>(ei, deg, E);
  k_rsqrt<<<gN, 256, 0, stream>>>(dinv, deg, N);
  k_scan<<<1, 1024, 0, stream>>>(deg, off, N);
  hipMemcpyAsync(cur, off, (size_t)N * 4, hipMemcpyDeviceToDevice, stream);
  k_scatter<<<(E + 255) / 256, 256, 0, stream>>>(ei, cur, srcs, E);

  // weight prep
  k_combine<<<2, 256, 0, stream>>>(in_w, in_b, out_w, out_b, Wc, bc);
  k_f32bf16_split<<<(16384 + 255) / 256, 256, 0, stream>>>(gcn_w, gcnh, gcnl, 16384);
  k_f32bf16_split<<<(32768 + 255) / 256, 256, 0, stream>>>(Wc, Wch, Wcl, 32768);
  k_f32bf16_split<<<(524288 + 255) / 256, 256, 0, stream>>>(ff1_w, ff1h, ff1l, 524288);
  k_f32bf16<<<(524288 + 255) / 256, 256, 0, stream>>>(ff2_w, ff2h, 524288);

  // GCN
  k_gemm_plain<<<gT, 512, 0, stream>>>(x, gcnh, gcnl, h0, N);
  k_gcn_agg<<<(N + 3) / 4, 256, 0, stream>>>(off, srcs, dinv, h0, gcn_b, Hb, N);

  // layer 0
  k_gemm_ln<<<gT, 512, 0, stream>>>(Hb, Wch, Wcl, bc, ln1_g, ln1_b, B1, N);
  k_ffn<<<gT, 512, 0, stream>>>(B1, ff1h, ff1l, ff1_b, ff2h, ff2_b, ln2_g, ln2_b, B2, N);
  // layer 1
  k_gemm_ln<<<gT, 512, 0, stream>>>(B2, Wch + 16384, Wcl + 16384, bc + 128,
                                    ln1_g + 128, ln1_b + 128, B1, N);
  k_ffn<<<gT, 512, 0, stream>>>(B1, ff1h + 262144, ff1l + 262144, ff1_b + 2048,
                                ff2h + 262144, ff2_b + 128, ln2_g + 128, ln2_b + 128, B2, N);

  k_final<<<gV, 256, 0, stream>>>(B2, Hb, out, N);
}